// Round 8
// baseline (914.274 us; speedup 1.0000x reference)
//
#include <hip/hip_runtime.h>
#include <hip/hip_cooperative_groups.h>
#include <math.h>

namespace cg = cooperative_groups;

#define N_NODES 50000
#define EDGES   800000
#define ETOT    (EDGES + N_NODES)
#define HID     128
#define NH      4

typedef __attribute__((ext_vector_type(8))) short short8;
typedef __attribute__((ext_vector_type(4))) float floatx4;

__device__ inline unsigned short f2bf(float f) {
    unsigned int u = __float_as_uint(f);
    u = u + 0x7FFFu + ((u >> 16) & 1u);   // RNE
    return (unsigned short)(u >> 16);
}

// ---------------------------------------------------------------------------
// CSR build bodies (r4/r6 proven bucketed form). cursor[] relative counts.
// ---------------------------------------------------------------------------
#define NB 391
#define BCAP 2688
#define CHUNK 4096
#define BIN_BLOCKS ((ETOT + CHUNK - 1) / CHUNK)   // 208
#define GEMM_TILES 782

__device__ __forceinline__ void bin_scatter_body(int* histL, int bid,
                                                 const int* __restrict__ ei,
                                                 int* __restrict__ cursor,
                                                 int* __restrict__ binned) {
    int t = threadIdx.x;
    __syncthreads();                    // safe LDS reuse across grid-stride iters
    for (int b = t; b < NB; b += 256) histL[b] = 0;
    __syncthreads();
    int base = bid * CHUNK;
#pragma unroll
    for (int j = 0; j < 16; j++) {
        int e = base + j * 256 + t;
        if (e < ETOT) {
            int d = (e < EDGES) ? ei[EDGES + e] : (e - EDGES);
            atomicAdd(&histL[d >> 7], 1);
        }
    }
    __syncthreads();
    for (int b = t; b < NB; b += 256) {
        int c = histL[b];
        histL[b] = c ? (b * BCAP + atomicAdd(&cursor[b], c)) : 0;  // global reservation
    }
    __syncthreads();
#pragma unroll
    for (int j = 0; j < 16; j++) {
        int e = base + j * 256 + t;
        if (e < ETOT) {
            int s, d;
            if (e < EDGES) { s = ei[e]; d = ei[EDGES + e]; }
            else           { s = d = e - EDGES; }
            int bb = d >> 7;
            int pos = atomicAdd(&histL[bb], 1);
            if (pos < (bb + 1) * BCAP)                 // safety clamp
                binned[pos] = (s << 7) | (d & 127);
        }
    }
}

__device__ __forceinline__ void bin_finalize_body(int* histN, int* excl, int b,
                                                  const int* __restrict__ binned,
                                                  const int* __restrict__ cursor,
                                                  int* __restrict__ starts,
                                                  int* __restrict__ degs,
                                                  int* __restrict__ csr) {
    int t = threadIdx.x;
    int n0 = b << 7;
    int S = b * BCAP;
    int cnt = cursor[b];                   // relative count
    if (cnt > BCAP) cnt = BCAP;
    __syncthreads();                       // safe LDS reuse across iters
    if (t < 128) histN[t] = 0;
    __syncthreads();
    for (int j = t; j < cnt; j += 256)
        atomicAdd(&histN[binned[S + j] & 127], 1);
    __syncthreads();
    int v = (t < 128) ? histN[t] : 0;
    if (t < 128) excl[t] = v;
    __syncthreads();
    for (int off = 1; off < 128; off <<= 1) {
        int x = 0, add = 0;
        if (t < 128) { x = excl[t]; if (t >= off) add = excl[t - off]; }
        __syncthreads();
        if (t < 128) excl[t] = x + add;
        __syncthreads();
    }
    if (t < 128) {
        int ex = excl[t] - v;
        int n = n0 + t;
        if (n < N_NODES) { starts[n] = S + ex; degs[n] = v; }
        histN[t] = ex;                 // reuse as within-bucket cursor
    }
    __syncthreads();
    for (int j = t; j < cnt; j += 256) {
        int e = binned[S + j];
        int pos = atomicAdd(&histN[e & 127], 1);
        csr[S + pos] = e >> 7;
    }
}

// ---------------------------------------------------------------------------
// W transpose + coef fold + cursor zero (virtual-block body).
// ---------------------------------------------------------------------------
__device__ __forceinline__ void wtrans_body(int vb,
        const float* W1, const float* W2,
        unsigned short* Wt1, unsigned short* Wt2,
        const float* b1, const float* g1, const float* be1, const float* mn1, const float* vr1,
        const float* b2, const float* g2, const float* be2, const float* mn2, const float* vr2,
        float* coef, int* cursor) {
    int i = vb * 256 + threadIdx.x;
    if (i < NB) cursor[i] = 0;
    if (i < 256 * 128) { int k = i >> 7, n = i & 127; Wt1[n * 256 + k] = f2bf(W1[i]); }
    if (i < 128 * 128) { int k = i >> 7, n = i & 127; Wt2[n * 128 + k] = f2bf(W2[i]); }
    if (vb == 0) {
        int t = threadIdx.x;
        if (t < 128) {
            float sc = g1[t] * rsqrtf(vr1[t] + 1e-5f);
            coef[t]       = sc;
            coef[128 + t] = be1[t] + (b1[t] - mn1[t]) * sc;
        } else {
            int c = t - 128;
            float sc = g2[c] * rsqrtf(vr2[c] + 1e-5f);
            coef[256 + c] = sc;
            coef[384 + c] = be2[c] + (b2[c] - mn2[c]) * sc;
        }
    }
}

// ---------------------------------------------------------------------------
// MFMA GEMM (bf16, fp32 acc) + fused att dots + bf16 H out (r1 proven form).
// ---------------------------------------------------------------------------
#define GR   64
#define KC   64
#define PADK 88
#define PADH 136

union Smem {
    struct { unsigned short Xs[GR][PADK]; unsigned short Ws[HID][PADK]; } s;
    unsigned short Hs[GR][PADH];
};

template<bool XBF16>
__device__ __forceinline__ void gemm_att_body(Smem& sm, int bid,
                                              const void* Xv,
                                              const unsigned short* Wt,
                                              const float* att_src,
                                              const float* att_dst,
                                              unsigned short* Hout,
                                              float* aS, float* aD, int K) {
    int t = threadIdx.x, lane = t & 63, w = t >> 6;
    int quad = lane >> 4, nl = lane & 15;
    int rowBase = bid * GR;

    __syncthreads();                    // safe LDS reuse across grid-stride iters

    floatx4 acc[8];
    floatx4 zero = {0.f, 0.f, 0.f, 0.f};
#pragma unroll
    for (int b = 0; b < 8; b++) acc[b] = zero;

    const float*          Xf = (const float*)Xv;
    const unsigned short* Xb = (const unsigned short*)Xv;

    for (int k0 = 0; k0 < K; k0 += KC) {
#pragma unroll
        for (int it = 0; it < 2; it++) {
            int s5 = t + it * 256;
            int row = s5 >> 3, kg = s5 & 7;
            int gr = rowBase + row;
            unsigned short tmp[8];
            if (XBF16) {
                uint4 v = make_uint4(0, 0, 0, 0);
                if (gr < N_NODES) v = *(const uint4*)&Xb[(unsigned)(gr * K + k0 + kg * 8)];
                *(uint4*)tmp = v;
            } else {
                float4 v0 = make_float4(0, 0, 0, 0), v1 = v0;
                if (gr < N_NODES) {
                    const float* p = &Xf[(unsigned)(gr * K + k0 + kg * 8)];
                    v0 = *(const float4*)p;
                    v1 = *(const float4*)(p + 4);
                }
                tmp[0] = f2bf(v0.x); tmp[1] = f2bf(v0.y); tmp[2] = f2bf(v0.z); tmp[3] = f2bf(v0.w);
                tmp[4] = f2bf(v1.x); tmp[5] = f2bf(v1.y); tmp[6] = f2bf(v1.z); tmp[7] = f2bf(v1.w);
            }
            *(uint4*)&sm.s.Xs[row][kg * 8] = *(uint4*)tmp;
        }
#pragma unroll
        for (int it = 0; it < 4; it++) {
            int s5 = t + it * 256;
            int n = s5 >> 3, kg = s5 & 7;
            *(uint4*)&sm.s.Ws[n][kg * 8] = *(const uint4*)&Wt[(unsigned)(n * K + k0 + kg * 8)];
        }
        __syncthreads();
#pragma unroll
        for (int ks = 0; ks < 2; ks++) {
            int kb = ks * 32 + quad * 8;
            short8 a0 = *(const short8*)&sm.s.Xs[w * 16 + nl][kb];
#pragma unroll
            for (int ct = 0; ct < 8; ct++) {
                short8 b = *(const short8*)&sm.s.Ws[ct * 16 + nl][kb];
                acc[ct] = __builtin_amdgcn_mfma_f32_16x16x32_bf16(a0, b, acc[ct], 0, 0, 0);
            }
        }
        __syncthreads();
    }

#pragma unroll
    for (int ct = 0; ct < 8; ct++)
#pragma unroll
        for (int r = 0; r < 4; r++)
            sm.Hs[w * 16 + quad * 4 + r][ct * 16 + nl] = f2bf(acc[ct][r]);

    float asv[8], adv[8];
    {
        const float* ap = &att_src[nl * 8];
        const float* dp = &att_dst[nl * 8];
        *(float4*)&asv[0] = *(const float4*)ap;  *(float4*)&asv[4] = *(const float4*)(ap + 4);
        *(float4*)&adv[0] = *(const float4*)dp;  *(float4*)&adv[4] = *(const float4*)(dp + 4);
    }
    int hd = nl >> 2;
#pragma unroll
    for (int it = 0; it < 4; it++) {
        int rl = w * 16 + it * 4 + quad;
        int grow = rowBase + rl;
        uint4 v = *(const uint4*)&sm.Hs[rl][nl * 8];
        float f[8];
        f[0] = __uint_as_float(v.x << 16); f[1] = __uint_as_float(v.x & 0xffff0000u);
        f[2] = __uint_as_float(v.y << 16); f[3] = __uint_as_float(v.y & 0xffff0000u);
        f[4] = __uint_as_float(v.z << 16); f[5] = __uint_as_float(v.z & 0xffff0000u);
        f[6] = __uint_as_float(v.w << 16); f[7] = __uint_as_float(v.w & 0xffff0000u);
        float ds = 0.f, dd = 0.f;
#pragma unroll
        for (int j = 0; j < 8; j++) {
            ds = fmaf(f[j], asv[j], ds);
            dd = fmaf(f[j], adv[j], dd);
        }
        ds += __shfl_xor(ds, 1); ds += __shfl_xor(ds, 2);
        dd += __shfl_xor(dd, 1); dd += __shfl_xor(dd, 2);
        if (grow < N_NODES) {
            *(uint4*)&Hout[(unsigned)(grow * HID + nl * 8)] = v;
            if ((nl & 3) == 0) { aS[grow * 4 + hd] = ds; aD[grow * 4 + hd] = dd; }
        }
    }
}

// ---------------------------------------------------------------------------
// Fused softmax + aggregate body (one wave per node; proven form, LDS-free).
// ---------------------------------------------------------------------------
#define ECAP 64

__device__ __forceinline__ void prefetchR(uint4 (&buf)[4], int sregr, const char* hbase,
                                          int sBase, int l16b) {
#pragma unroll
    for (int u = 0; u < 4; u++) {
        int se = __builtin_amdgcn_ds_bpermute(sBase | (u << 2), sregr);
        buf[u] = *(const uint4*)(hbase + (((long)se) << 8) + l16b);
    }
}

__device__ __forceinline__ void consumeR(const uint4 (&buf)[4], float xrr, int aBase,
                                         float (&acc)[8]) {
#pragma unroll
    for (int u = 0; u < 4; u++) {
        float au = __uint_as_float((unsigned)__builtin_amdgcn_ds_bpermute(
                        aBase | (u << 2), (int)__float_as_uint(xrr)));
        uint4 v = buf[u];
        acc[0] = fmaf(__uint_as_float(v.x << 16),         au, acc[0]);
        acc[1] = fmaf(__uint_as_float(v.x & 0xffff0000u), au, acc[1]);
        acc[2] = fmaf(__uint_as_float(v.y << 16),         au, acc[2]);
        acc[3] = fmaf(__uint_as_float(v.y & 0xffff0000u), au, acc[3]);
        acc[4] = fmaf(__uint_as_float(v.z << 16),         au, acc[4]);
        acc[5] = fmaf(__uint_as_float(v.z & 0xffff0000u), au, acc[5]);
        acc[6] = fmaf(__uint_as_float(v.w << 16),         au, acc[6]);
        acc[7] = fmaf(__uint_as_float(v.w & 0xffff0000u), au, acc[7]);
    }
}

template<bool OUTBF16>
__device__ __forceinline__ void gather_body(int nb,
                                            const unsigned short* hfeat,
                                            const float* a_s, const float* a_d,
                                            const int* starts, const int* degs,
                                            const int* csr,
                                            const float* coefA, const float* coefB,
                                            void* outv) {
    int t = threadIdx.x, lane = t & 63, ws = t >> 6;
    int h = lane >> 4, l16 = lane & 15;
    int n = nb * 4 + ws;
    int start = starts[n];
    int deg = degs[n];
    float adh = a_d[(unsigned)(n * 4 + h)];
    const char* hbase = (const char*)hfeat;
    int sBase = lane & 48;
    int aBase = ((lane & 12) << 4) | sBase;
    int l16b = l16 << 4;

    int sreg[4];
#pragma unroll
    for (int it = 0; it < 4; it++) {
        int j = l16 + it * 16;
        sreg[it] = (j < deg) ? csr[start + j] : 0;
    }
    float e[4];
#pragma unroll
    for (int it = 0; it < 4; it++) {
        int j = l16 + it * 16;
        e[it] = -1e30f;
        if (j < deg) {
            float as = a_s[(unsigned)(sreg[it] * 4 + h)];
            float v = as + adh;
            e[it] = v > 0.f ? v : 0.2f * v;
        }
    }

    int cap = deg < ECAP ? deg : ECAP;
    uint4 vA[4], vB[4];
    prefetchR(vA, sreg[0], hbase, sBase, l16b);
    if (cap > 16) prefetchR(vB, sreg[1], hbase, sBase, l16b);

    float m = fmaxf(fmaxf(e[0], e[1]), fmaxf(e[2], e[3]));
    for (int j = ECAP + l16; j < deg; j += 16) {
        int s = csr[start + j];
        float as = a_s[(unsigned)(s * 4 + h)];
        float v = as + adh; v = v > 0.f ? v : 0.2f * v;
        m = fmaxf(m, v);
    }
#pragma unroll
    for (int off = 1; off < 16; off <<= 1) m = fmaxf(m, __shfl_xor(m, off));

    float x[4];
    float d = 0.f;
#pragma unroll
    for (int it = 0; it < 4; it++) { x[it] = __expf(e[it] - m); d += x[it]; }
    for (int j = ECAP + l16; j < deg; j += 16) {
        int s = csr[start + j];
        float as = a_s[(unsigned)(s * 4 + h)];
        float v = as + adh; v = v > 0.f ? v : 0.2f * v;
        d += __expf(v - m);
    }
#pragma unroll
    for (int off = 1; off < 16; off <<= 1) d += __shfl_xor(d, off);
    float rd = 1.0f / (d + 1e-16f);
    float xr[4];
#pragma unroll
    for (int it = 0; it < 4; it++) xr[it] = x[it] * rd;

    float acc[8];
#pragma unroll
    for (int j = 0; j < 8; j++) acc[j] = 0.f;
    consumeR(vA, xr[0], aBase, acc);
    if (cap > 16) {
        if (cap > 32) prefetchR(vA, sreg[2], hbase, sBase, l16b);
        consumeR(vB, xr[1], aBase, acc);
        if (cap > 32) {
            if (cap > 48) prefetchR(vB, sreg[3], hbase, sBase, l16b);
            consumeR(vA, xr[2], aBase, acc);
            if (cap > 48) consumeR(vB, xr[3], aBase, acc);
        }
    }
    if (deg > ECAP) {                                    // rare serial tail
        int hh = l16 >> 2;
        int gB = (lane & 12) << 4;
        float mB  = __uint_as_float((unsigned)__builtin_amdgcn_ds_bpermute(gB, (int)__float_as_uint(m)));
        float rdB = __uint_as_float((unsigned)__builtin_amdgcn_ds_bpermute(gB, (int)__float_as_uint(rd)));
        float adhB = a_d[(unsigned)(n * 4 + hh)];
        for (int j = ECAP; j < deg; j++) {
            int s = csr[start + j];
            float asv = a_s[(unsigned)(s * 4 + hh)];
            float v2 = asv + adhB; v2 = v2 > 0.f ? v2 : 0.2f * v2;
            float al = __expf(v2 - mB) * rdB;
            uint4 v = *(const uint4*)(hbase + (((long)s) << 8) + l16b);
            acc[0] = fmaf(__uint_as_float(v.x << 16),         al, acc[0]);
            acc[1] = fmaf(__uint_as_float(v.x & 0xffff0000u), al, acc[1]);
            acc[2] = fmaf(__uint_as_float(v.y << 16),         al, acc[2]);
            acc[3] = fmaf(__uint_as_float(v.y & 0xffff0000u), al, acc[3]);
            acc[4] = fmaf(__uint_as_float(v.z << 16),         al, acc[4]);
            acc[5] = fmaf(__uint_as_float(v.z & 0xffff0000u), al, acc[5]);
            acc[6] = fmaf(__uint_as_float(v.w << 16),         al, acc[6]);
            acc[7] = fmaf(__uint_as_float(v.w & 0xffff0000u), al, acc[7]);
        }
    }

#pragma unroll
    for (int j = 0; j < 8; j++) {
        acc[j] += __shfl_xor(acc[j], 16);
        acc[j] += __shfl_xor(acc[j], 32);
    }

    int g = lane >> 4;
    float o0 = acc[0], o1 = acc[1];
    if (g == 1) { o0 = acc[2]; o1 = acc[3]; }
    if (g == 2) { o0 = acc[4]; o1 = acc[5]; }
    if (g == 3) { o0 = acc[6]; o1 = acc[7]; }
    int c = (l16 << 3) + (g << 1);
    float2 cA = *(const float2*)&coefA[c];
    float2 cB = *(const float2*)&coefB[c];
    float r0 = fmaxf(fmaf(o0, cA.x, cB.x), 0.f);
    float r1 = fmaxf(fmaf(o1, cA.y, cB.y), 0.f);
    unsigned oidx = (unsigned)(n * 64 + (l16 << 2) + g);
    if (OUTBF16) {
        unsigned int pk = (unsigned int)f2bf(r0) | ((unsigned int)f2bf(r1) << 16);
        ((unsigned int*)outv)[oidx] = pk;
    } else {
        ((float2*)outv)[oidx] = make_float2(r0, r1);
    }
}

// ---------------------------------------------------------------------------
// Persistent cooperative mega-kernel: all phases, grid syncs between them.
// Replaces 6 dispatch boundaries (~12-15us each) with 5 grid syncs (~3-5us).
// ---------------------------------------------------------------------------
struct MegaArgs {
    const int* ei; const float* x;
    const float* W1; const float* W2;
    const float* as1; const float* ad1;
    const float* b1; const float* g1; const float* be1; const float* mn1; const float* vr1;
    const float* as2; const float* ad2;
    const float* b2; const float* g2; const float* be2; const float* mn2; const float* vr2;
    unsigned short* Wt1; unsigned short* Wt2;
    unsigned short* hbA; unsigned short* x2b; unsigned short* hbB;
    float* aS1; float* aD1; float* aS2; float* aD2;
    float* coef; int* cursor; int* starts; int* degs; int* binned; int* csr;
    float* out;
};

__global__ __launch_bounds__(256, 4) void mega_kernel(MegaArgs a) {
    cg::grid_group grid = cg::this_grid();
    __shared__ Smem sm;
    __shared__ int histL[NB];
    __shared__ int histN[128];
    __shared__ int excl[128];
    int bid = blockIdx.x, G = gridDim.x;

    // P0: wtrans + coef + cursor zero
    for (int vb = bid; vb < 128; vb += G)
        wtrans_body(vb, a.W1, a.W2, a.Wt1, a.Wt2, a.b1, a.g1, a.be1, a.mn1, a.vr1,
                    a.b2, a.g2, a.be2, a.mn2, a.vr2, a.coef, a.cursor);
    __threadfence();
    grid.sync();

    // P1: CSR bucket scatter (208) || GEMM1 (782)
    for (int vb = bid; vb < BIN_BLOCKS + GEMM_TILES; vb += G) {
        if (vb < BIN_BLOCKS)
            bin_scatter_body(histL, vb, a.ei, a.cursor, a.binned);
        else
            gemm_att_body<false>(sm, vb - BIN_BLOCKS, a.x, a.Wt1, a.as1, a.ad1,
                                 a.hbA, a.aS1, a.aD1, 256);
    }
    __threadfence();
    grid.sync();

    // P2: bucket finalize (391)
    for (int vb = bid; vb < NB; vb += G)
        bin_finalize_body(histN, excl, vb, a.binned, a.cursor, a.starts, a.degs, a.csr);
    __threadfence();
    grid.sync();

    // P3: gather layer 1 (12500 node-groups)
    for (int vb = bid; vb < N_NODES / 4; vb += G)
        gather_body<true>(vb, a.hbA, a.aS1, a.aD1, a.starts, a.degs, a.csr,
                          a.coef, a.coef + 128, (void*)a.x2b);
    __threadfence();
    grid.sync();

    // P4: GEMM2 (782)
    for (int vb = bid; vb < GEMM_TILES; vb += G)
        gemm_att_body<true>(sm, vb, a.x2b, a.Wt2, a.as2, a.ad2, a.hbB, a.aS2, a.aD2, 128);
    __threadfence();
    grid.sync();

    // P5: gather layer 2 (12500 node-groups)
    for (int vb = bid; vb < N_NODES / 4; vb += G)
        gather_body<false>(vb, a.hbB, a.aS2, a.aD2, a.starts, a.degs, a.csr,
                           a.coef + 256, a.coef + 384, (void*)a.out);
}

// ---------------------------------------------------------------------------
// Fallback dispatch wrappers (r6 proven schedule, 251.2us measured)
// ---------------------------------------------------------------------------
__global__ void wtrans_coef_kernel(const float* W1, const float* W2,
                                   unsigned short* Wt1, unsigned short* Wt2,
                                   const float* b1, const float* g1, const float* be1,
                                   const float* mn1, const float* vr1,
                                   const float* b2, const float* g2, const float* be2,
                                   const float* mn2, const float* vr2,
                                   float* coef, int* cursor) {
    wtrans_body(blockIdx.x, W1, W2, Wt1, Wt2, b1, g1, be1, mn1, vr1,
                b2, g2, be2, mn2, vr2, coef, cursor);
}

__global__ __launch_bounds__(256) void fused_scatter_gemm1a(
        const int* ei, int* cursor, int* binned,
        const float* x, const unsigned short* Wt1,
        const float* att_src, const float* att_dst,
        unsigned short* Hout, float* aS, float* aD) {
    __shared__ Smem sm;
    __shared__ int histL[NB];
    if (blockIdx.x < BIN_BLOCKS) {
        bin_scatter_body(histL, blockIdx.x, ei, cursor, binned);
    } else {
        gemm_att_body<false>(sm, blockIdx.x - BIN_BLOCKS, x, Wt1, att_src, att_dst,
                             Hout, aS, aD, 256);
    }
}

__global__ __launch_bounds__(256) void fused_finalize_gemm1b(
        const int* binned, const int* cursor,
        int* starts, int* degs, int* csr,
        const float* x, const unsigned short* Wt1,
        const float* att_src, const float* att_dst,
        unsigned short* Hout, float* aS, float* aD) {
    __shared__ Smem sm;
    __shared__ int histN[128];
    __shared__ int excl[128];
    if (blockIdx.x < NB) {
        bin_finalize_body(histN, excl, blockIdx.x, binned, cursor, starts, degs, csr);
    } else {
        gemm_att_body<false>(sm, blockIdx.x, x, Wt1, att_src, att_dst,
                             Hout, aS, aD, 256);
    }
}

template<bool XBF16>
__global__ __launch_bounds__(256) void gemm_att_kernel(const void* Xv,
                                                       const unsigned short* Wt,
                                                       const float* att_src,
                                                       const float* att_dst,
                                                       unsigned short* Hout,
                                                       float* aS, float* aD, int K) {
    __shared__ Smem sm;
    gemm_att_body<XBF16>(sm, blockIdx.x, Xv, Wt, att_src, att_dst, Hout, aS, aD, K);
}

template<bool OUTBF16>
__global__ __launch_bounds__(256) void gather_kernel(const unsigned short* hfeat,
                                                     const float* a_s, const float* a_d,
                                                     const int* starts, const int* degs,
                                                     const int* csr,
                                                     const float* coefA, const float* coefB,
                                                     void* outv) {
    gather_body<OUTBF16>((int)blockIdx.x, hfeat, a_s, a_d, starts, degs, csr,
                         coefA, coefB, outv);
}

// ---------------------------------------------------------------------------
extern "C" void kernel_launch(void* const* d_in, const int* in_sizes, int n_in,
                              void* d_out, int out_size, void* d_ws, size_t ws_size,
                              hipStream_t stream) {
    const float* x    = (const float*)d_in[0];
    const int*   ei   = (const int*)d_in[1];
    const float* W1   = (const float*)d_in[2];
    const float* as1  = (const float*)d_in[3];
    const float* ad1  = (const float*)d_in[4];
    const float* b1   = (const float*)d_in[5];
    const float* g1   = (const float*)d_in[6];
    const float* be1  = (const float*)d_in[7];
    const float* mn1  = (const float*)d_in[8];
    const float* vr1  = (const float*)d_in[9];
    const float* W2   = (const float*)d_in[10];
    const float* as2  = (const float*)d_in[11];
    const float* ad2  = (const float*)d_in[12];
    const float* b2   = (const float*)d_in[13];
    const float* g2   = (const float*)d_in[14];
    const float* be2  = (const float*)d_in[15];
    const float* mn2  = (const float*)d_in[16];
    const float* vr2  = (const float*)d_in[17];
    float* out = (float*)d_out;

    unsigned short* hbA = (unsigned short*)d_ws;                  // N*128 bf16
    unsigned short* x2b = hbA + (size_t)N_NODES * HID;            // N*128 bf16
    unsigned short* Wt1 = x2b + (size_t)N_NODES * HID;            // 128*256
    unsigned short* Wt2 = Wt1 + 128 * 256;                        // 128*128
    float* aS1   = (float*)(Wt2 + 128 * 128);                     // N*4
    float* aD1   = aS1 + N_NODES * NH;                            // N*4
    float* aS2   = aD1 + N_NODES * NH;                            // N*4
    float* aD2   = aS2 + N_NODES * NH;                            // N*4
    float* coef  = aD2 + N_NODES * NH;                            // 512
    int* cursor  = (int*)(coef + 512);                            // 512 (padded)
    int* starts  = cursor + 512;                                  // N
    int* degs    = starts + N_NODES;                              // N
    int* csr     = degs + N_NODES;                                // NB*BCAP
    int* binned  = csr + NB * BCAP;                               // NB*BCAP
    unsigned short* hbB = (unsigned short*)binned;                // overlay (disjoint live range)

    size_t need = (size_t)((char*)binned - (char*)d_ws) + (size_t)N_NODES * HID * 2;
    bool big = ws_size >= need;
    if (!big) { hbB = hbA; aS2 = aS1; aD2 = aD1; }

    // one-time cooperative-launch capability + grid sizing
    static int megaGrid = 0;   // 0 = unprobed, -1 = unavailable, >0 = grid size
    if (megaGrid == 0) {
        int coop = 0, numCU = 0, blocksPerCU = 0;
        hipDeviceGetAttribute(&coop, hipDeviceAttributeCooperativeLaunch, 0);
        hipDeviceGetAttribute(&numCU, hipDeviceAttributeMultiprocessorCount, 0);
        hipError_t e = hipOccupancyMaxActiveBlocksPerMultiprocessor(
            &blocksPerCU, (const void*)mega_kernel, 256, 0);
        if (coop && numCU > 0 && e == hipSuccess && blocksPerCU > 0)
            megaGrid = blocksPerCU * numCU;
        else
            megaGrid = -1;
    }

    if (megaGrid > 0) {
        MegaArgs a = { ei, x, W1, W2, as1, ad1, b1, g1, be1, mn1, vr1,
                       as2, ad2, b2, g2, be2, mn2, vr2,
                       Wt1, Wt2, hbA, x2b, hbB, aS1, aD1, aS2, aD2,
                       coef, cursor, starts, degs, binned, csr, out };
        void* kp[] = { (void*)&a };
        hipError_t err = hipLaunchCooperativeKernel((const void*)mega_kernel,
                                                    dim3(megaGrid), dim3(256),
                                                    kp, 0, stream);
        if (err == hipSuccess) return;
        megaGrid = -1;   // fall through to dispatch schedule
    }

    // fallback: r6 proven dispatch schedule
    int gemmGrid = GEMM_TILES;
    int nodeGrid = N_NODES / 4;
    wtrans_coef_kernel<<<128, 256, 0, stream>>>(W1, W2, Wt1, Wt2,
                                                b1, g1, be1, mn1, vr1,
                                                b2, g2, be2, mn2, vr2, coef, cursor);
    fused_scatter_gemm1a<<<BIN_BLOCKS + NB, 256, 0, stream>>>(
        ei, cursor, binned, x, Wt1, as1, ad1, hbA, aS1, aD1);
    fused_finalize_gemm1b<<<gemmGrid, 256, 0, stream>>>(
        binned, cursor, starts, degs, csr, x, Wt1, as1, ad1, hbA, aS1, aD1);
    gather_kernel<true><<<nodeGrid, 256, 0, stream>>>(hbA, aS1, aD1, starts, degs, csr,
                                                      coef, coef + 128, (void*)x2b);
    gemm_att_kernel<true><<<gemmGrid, 256, 0, stream>>>(x2b, Wt2, as2, ad2, hbB, aS2, aD2, 128);
    gather_kernel<false><<<nodeGrid, 256, 0, stream>>>(hbB, aS2, aD2, starts, degs, csr,
                                                       coef + 256, coef + 384, (void*)out);
}

// Round 9
// 246.939 us; speedup vs baseline: 3.7024x; 3.7024x over previous
//
#include <hip/hip_runtime.h>
#include <math.h>

#define N_NODES 50000
#define EDGES   800000
#define ETOT    (EDGES + N_NODES)
#define HID     128
#define NH      4

typedef __attribute__((ext_vector_type(8))) short short8;
typedef __attribute__((ext_vector_type(4))) float floatx4;

__device__ inline unsigned short f2bf(float f) {
    unsigned int u = __float_as_uint(f);
    u = u + 0x7FFFu + ((u >> 16) & 1u);   // RNE
    return (unsigned short)(u >> 16);
}

// ---------------------------------------------------------------------------
// CSR build: bucketed scatter + per-bucket finalize (r4/r6 proven form).
// cursor[] relative counts, zeroed by wtrans.
// ---------------------------------------------------------------------------
#define NB 391
#define BCAP 2688
#define CHUNK 4096
#define BIN_BLOCKS ((ETOT + CHUNK - 1) / CHUNK)   // 208
#define GEMM_TILES 782

__device__ __forceinline__ void bin_scatter_body(int* histL, int bid,
                                                 const int* __restrict__ ei,
                                                 int* __restrict__ cursor,
                                                 int* __restrict__ binned) {
    int t = threadIdx.x;
    for (int b = t; b < NB; b += 256) histL[b] = 0;
    __syncthreads();
    int base = bid * CHUNK;
#pragma unroll
    for (int j = 0; j < 16; j++) {
        int e = base + j * 256 + t;
        if (e < ETOT) {
            int d = (e < EDGES) ? ei[EDGES + e] : (e - EDGES);
            atomicAdd(&histL[d >> 7], 1);
        }
    }
    __syncthreads();
    for (int b = t; b < NB; b += 256) {
        int c = histL[b];
        histL[b] = c ? (b * BCAP + atomicAdd(&cursor[b], c)) : 0;  // global reservation
    }
    __syncthreads();
#pragma unroll
    for (int j = 0; j < 16; j++) {
        int e = base + j * 256 + t;
        if (e < ETOT) {
            int s, d;
            if (e < EDGES) { s = ei[e]; d = ei[EDGES + e]; }
            else           { s = d = e - EDGES; }
            int bb = d >> 7;
            int pos = atomicAdd(&histL[bb], 1);
            if (pos < (bb + 1) * BCAP)                 // safety clamp
                binned[pos] = (s << 7) | (d & 127);
        }
    }
}

__device__ __forceinline__ void bin_finalize_body(int* histN, int* excl, int b,
                                                  const int* __restrict__ binned,
                                                  const int* __restrict__ cursor,
                                                  int* __restrict__ starts,
                                                  int* __restrict__ degs,
                                                  int* __restrict__ csr) {
    int t = threadIdx.x;
    int n0 = b << 7;
    int S = b * BCAP;
    int cnt = cursor[b];                   // relative count
    if (cnt > BCAP) cnt = BCAP;
    if (t < 128) histN[t] = 0;
    __syncthreads();
    for (int j = t; j < cnt; j += 256)
        atomicAdd(&histN[binned[S + j] & 127], 1);
    __syncthreads();
    int v = (t < 128) ? histN[t] : 0;
    if (t < 128) excl[t] = v;
    __syncthreads();
    for (int off = 1; off < 128; off <<= 1) {
        int x = 0, add = 0;
        if (t < 128) { x = excl[t]; if (t >= off) add = excl[t - off]; }
        __syncthreads();
        if (t < 128) excl[t] = x + add;
        __syncthreads();
    }
    if (t < 128) {
        int ex = excl[t] - v;
        int n = n0 + t;
        if (n < N_NODES) { starts[n] = S + ex; degs[n] = v; }
        histN[t] = ex;                 // reuse as within-bucket cursor
    }
    __syncthreads();
    for (int j = t; j < cnt; j += 256) {
        int e = binned[S + j];
        int pos = atomicAdd(&histN[e & 127], 1);
        csr[S + pos] = e >> 7;
    }
}

// ---------------------------------------------------------------------------
// W transpose + bf16 convert; block 0 folds bias+BN into coef; zeroes cursor.
// ---------------------------------------------------------------------------
__global__ void wtrans_coef_kernel(const float* __restrict__ W1, const float* __restrict__ W2,
                                   unsigned short* __restrict__ Wt1, unsigned short* __restrict__ Wt2,
                                   const float* __restrict__ b1, const float* __restrict__ g1,
                                   const float* __restrict__ be1, const float* __restrict__ mn1,
                                   const float* __restrict__ vr1,
                                   const float* __restrict__ b2, const float* __restrict__ g2,
                                   const float* __restrict__ be2, const float* __restrict__ mn2,
                                   const float* __restrict__ vr2, float* __restrict__ coef,
                                   int* __restrict__ cursor) {
    int i = blockIdx.x * 256 + threadIdx.x;
    if (i < NB) cursor[i] = 0;
    if (i < 256 * 128) { int k = i >> 7, n = i & 127; Wt1[n * 256 + k] = f2bf(W1[i]); }
    if (i < 128 * 128) { int k = i >> 7, n = i & 127; Wt2[n * 128 + k] = f2bf(W2[i]); }
    if (blockIdx.x == 0) {
        int t = threadIdx.x;
        if (t < 128) {
            float sc = g1[t] * rsqrtf(vr1[t] + 1e-5f);
            coef[t]       = sc;
            coef[128 + t] = be1[t] + (b1[t] - mn1[t]) * sc;
        } else {
            int c = t - 128;
            float sc = g2[c] * rsqrtf(vr2[c] + 1e-5f);
            coef[256 + c] = sc;
            coef[384 + c] = be2[c] + (b2[c] - mn2[c]) * sc;
        }
    }
}

// ---------------------------------------------------------------------------
// MFMA GEMM (bf16, fp32 acc) + fused att dots + bf16 H out (r1 proven form).
// PADK=72 (was 88): same 2-way (free) bank aliasing class, 16B-aligned rows,
// Smem 35.4KB -> 27.6KB => gemm dispatches go 4 -> 5 blocks/CU (latency-bound,
// +25% resident waves).
// ---------------------------------------------------------------------------
#define GR   64
#define KC   64
#define PADK 72
#define PADH 136

union Smem {
    struct { unsigned short Xs[GR][PADK]; unsigned short Ws[HID][PADK]; } s;
    unsigned short Hs[GR][PADH];
};

template<bool XBF16>
__device__ __forceinline__ void gemm_att_body(Smem& sm, int bid,
                                              const void* Xv,
                                              const unsigned short* Wt,
                                              const float* att_src,
                                              const float* att_dst,
                                              unsigned short* Hout,
                                              float* aS, float* aD, int K) {
    int t = threadIdx.x, lane = t & 63, w = t >> 6;
    int quad = lane >> 4, nl = lane & 15;
    int rowBase = bid * GR;

    floatx4 acc[8];
    floatx4 zero = {0.f, 0.f, 0.f, 0.f};
#pragma unroll
    for (int b = 0; b < 8; b++) acc[b] = zero;

    const float*          Xf = (const float*)Xv;
    const unsigned short* Xb = (const unsigned short*)Xv;

    for (int k0 = 0; k0 < K; k0 += KC) {
#pragma unroll
        for (int it = 0; it < 2; it++) {
            int s5 = t + it * 256;
            int row = s5 >> 3, kg = s5 & 7;
            int gr = rowBase + row;
            unsigned short tmp[8];
            if (XBF16) {
                uint4 v = make_uint4(0, 0, 0, 0);
                if (gr < N_NODES) v = *(const uint4*)&Xb[(unsigned)(gr * K + k0 + kg * 8)];
                *(uint4*)tmp = v;
            } else {
                float4 v0 = make_float4(0, 0, 0, 0), v1 = v0;
                if (gr < N_NODES) {
                    const float* p = &Xf[(unsigned)(gr * K + k0 + kg * 8)];
                    v0 = *(const float4*)p;
                    v1 = *(const float4*)(p + 4);
                }
                tmp[0] = f2bf(v0.x); tmp[1] = f2bf(v0.y); tmp[2] = f2bf(v0.z); tmp[3] = f2bf(v0.w);
                tmp[4] = f2bf(v1.x); tmp[5] = f2bf(v1.y); tmp[6] = f2bf(v1.z); tmp[7] = f2bf(v1.w);
            }
            *(uint4*)&sm.s.Xs[row][kg * 8] = *(uint4*)tmp;
        }
#pragma unroll
        for (int it = 0; it < 4; it++) {
            int s5 = t + it * 256;
            int n = s5 >> 3, kg = s5 & 7;
            *(uint4*)&sm.s.Ws[n][kg * 8] = *(const uint4*)&Wt[(unsigned)(n * K + k0 + kg * 8)];
        }
        __syncthreads();
#pragma unroll
        for (int ks = 0; ks < 2; ks++) {
            int kb = ks * 32 + quad * 8;
            short8 a0 = *(const short8*)&sm.s.Xs[w * 16 + nl][kb];
#pragma unroll
            for (int ct = 0; ct < 8; ct++) {
                short8 b = *(const short8*)&sm.s.Ws[ct * 16 + nl][kb];
                acc[ct] = __builtin_amdgcn_mfma_f32_16x16x32_bf16(a0, b, acc[ct], 0, 0, 0);
            }
        }
        __syncthreads();
    }

#pragma unroll
    for (int ct = 0; ct < 8; ct++)
#pragma unroll
        for (int r = 0; r < 4; r++)
            sm.Hs[w * 16 + quad * 4 + r][ct * 16 + nl] = f2bf(acc[ct][r]);

    float asv[8], adv[8];
    {
        const float* ap = &att_src[nl * 8];
        const float* dp = &att_dst[nl * 8];
        *(float4*)&asv[0] = *(const float4*)ap;  *(float4*)&asv[4] = *(const float4*)(ap + 4);
        *(float4*)&adv[0] = *(const float4*)dp;  *(float4*)&adv[4] = *(const float4*)(dp + 4);
    }
    int hd = nl >> 2;
#pragma unroll
    for (int it = 0; it < 4; it++) {
        int rl = w * 16 + it * 4 + quad;
        int grow = rowBase + rl;
        uint4 v = *(const uint4*)&sm.Hs[rl][nl * 8];
        float f[8];
        f[0] = __uint_as_float(v.x << 16); f[1] = __uint_as_float(v.x & 0xffff0000u);
        f[2] = __uint_as_float(v.y << 16); f[3] = __uint_as_float(v.y & 0xffff0000u);
        f[4] = __uint_as_float(v.z << 16); f[5] = __uint_as_float(v.z & 0xffff0000u);
        f[6] = __uint_as_float(v.w << 16); f[7] = __uint_as_float(v.w & 0xffff0000u);
        float ds = 0.f, dd = 0.f;
#pragma unroll
        for (int j = 0; j < 8; j++) {
            ds = fmaf(f[j], asv[j], ds);
            dd = fmaf(f[j], adv[j], dd);
        }
        ds += __shfl_xor(ds, 1); ds += __shfl_xor(ds, 2);
        dd += __shfl_xor(dd, 1); dd += __shfl_xor(dd, 2);
        if (grow < N_NODES) {
            *(uint4*)&Hout[(unsigned)(grow * HID + nl * 8)] = v;
            if ((nl & 3) == 0) { aS[grow * 4 + hd] = ds; aD[grow * 4 + hd] = dd; }
        }
    }
}

// ---------------------------------------------------------------------------
// Fused softmax + aggregate body (one wave per node; proven form, LDS-free).
// At the random-access compulsory-fetch floor (~46us, invariant across 3
// structures; FETCH ~= 8 XCD x hb working set).
// ---------------------------------------------------------------------------
#define ECAP 64

__device__ __forceinline__ void prefetchR(uint4 (&buf)[4], int sregr, const char* hbase,
                                          int sBase, int l16b) {
#pragma unroll
    for (int u = 0; u < 4; u++) {
        int se = __builtin_amdgcn_ds_bpermute(sBase | (u << 2), sregr);
        buf[u] = *(const uint4*)(hbase + (((long)se) << 8) + l16b);
    }
}

__device__ __forceinline__ void consumeR(const uint4 (&buf)[4], float xrr, int aBase,
                                         float (&acc)[8]) {
#pragma unroll
    for (int u = 0; u < 4; u++) {
        float au = __uint_as_float((unsigned)__builtin_amdgcn_ds_bpermute(
                        aBase | (u << 2), (int)__float_as_uint(xrr)));
        uint4 v = buf[u];
        acc[0] = fmaf(__uint_as_float(v.x << 16),         au, acc[0]);
        acc[1] = fmaf(__uint_as_float(v.x & 0xffff0000u), au, acc[1]);
        acc[2] = fmaf(__uint_as_float(v.y << 16),         au, acc[2]);
        acc[3] = fmaf(__uint_as_float(v.y & 0xffff0000u), au, acc[3]);
        acc[4] = fmaf(__uint_as_float(v.z << 16),         au, acc[4]);
        acc[5] = fmaf(__uint_as_float(v.z & 0xffff0000u), au, acc[5]);
        acc[6] = fmaf(__uint_as_float(v.w << 16),         au, acc[6]);
        acc[7] = fmaf(__uint_as_float(v.w & 0xffff0000u), au, acc[7]);
    }
}

template<bool OUTBF16>
__device__ __forceinline__ void gather_body(int nb,
                                            const unsigned short* hfeat,
                                            const float* a_s, const float* a_d,
                                            const int* starts, const int* degs,
                                            const int* csr,
                                            const float* coefA, const float* coefB,
                                            void* outv) {
    int t = threadIdx.x, lane = t & 63, ws = t >> 6;
    int h = lane >> 4, l16 = lane & 15;
    int n = nb * 4 + ws;
    int start = starts[n];
    int deg = degs[n];
    float adh = a_d[(unsigned)(n * 4 + h)];
    const char* hbase = (const char*)hfeat;
    int sBase = lane & 48;
    int aBase = ((lane & 12) << 4) | sBase;
    int l16b = l16 << 4;

    int sreg[4];
#pragma unroll
    for (int it = 0; it < 4; it++) {
        int j = l16 + it * 16;
        sreg[it] = (j < deg) ? csr[start + j] : 0;
    }
    float e[4];
#pragma unroll
    for (int it = 0; it < 4; it++) {
        int j = l16 + it * 16;
        e[it] = -1e30f;
        if (j < deg) {
            float as = a_s[(unsigned)(sreg[it] * 4 + h)];
            float v = as + adh;
            e[it] = v > 0.f ? v : 0.2f * v;
        }
    }

    int cap = deg < ECAP ? deg : ECAP;
    uint4 vA[4], vB[4];
    prefetchR(vA, sreg[0], hbase, sBase, l16b);
    if (cap > 16) prefetchR(vB, sreg[1], hbase, sBase, l16b);

    float m = fmaxf(fmaxf(e[0], e[1]), fmaxf(e[2], e[3]));
    for (int j = ECAP + l16; j < deg; j += 16) {
        int s = csr[start + j];
        float as = a_s[(unsigned)(s * 4 + h)];
        float v = as + adh; v = v > 0.f ? v : 0.2f * v;
        m = fmaxf(m, v);
    }
#pragma unroll
    for (int off = 1; off < 16; off <<= 1) m = fmaxf(m, __shfl_xor(m, off));

    float x[4];
    float d = 0.f;
#pragma unroll
    for (int it = 0; it < 4; it++) { x[it] = __expf(e[it] - m); d += x[it]; }
    for (int j = ECAP + l16; j < deg; j += 16) {
        int s = csr[start + j];
        float as = a_s[(unsigned)(s * 4 + h)];
        float v = as + adh; v = v > 0.f ? v : 0.2f * v;
        d += __expf(v - m);
    }
#pragma unroll
    for (int off = 1; off < 16; off <<= 1) d += __shfl_xor(d, off);
    float rd = 1.0f / (d + 1e-16f);
    float xr[4];
#pragma unroll
    for (int it = 0; it < 4; it++) xr[it] = x[it] * rd;

    float acc[8];
#pragma unroll
    for (int j = 0; j < 8; j++) acc[j] = 0.f;
    consumeR(vA, xr[0], aBase, acc);
    if (cap > 16) {
        if (cap > 32) prefetchR(vA, sreg[2], hbase, sBase, l16b);
        consumeR(vB, xr[1], aBase, acc);
        if (cap > 32) {
            if (cap > 48) prefetchR(vB, sreg[3], hbase, sBase, l16b);
            consumeR(vA, xr[2], aBase, acc);
            if (cap > 48) consumeR(vB, xr[3], aBase, acc);
        }
    }
    if (deg > ECAP) {                                    // rare serial tail
        int hh = l16 >> 2;
        int gB = (lane & 12) << 4;
        float mB  = __uint_as_float((unsigned)__builtin_amdgcn_ds_bpermute(gB, (int)__float_as_uint(m)));
        float rdB = __uint_as_float((unsigned)__builtin_amdgcn_ds_bpermute(gB, (int)__float_as_uint(rd)));
        float adhB = a_d[(unsigned)(n * 4 + hh)];
        for (int j = ECAP; j < deg; j++) {
            int s = csr[start + j];
            float asv = a_s[(unsigned)(s * 4 + hh)];
            float v2 = asv + adhB; v2 = v2 > 0.f ? v2 : 0.2f * v2;
            float al = __expf(v2 - mB) * rdB;
            uint4 v = *(const uint4*)(hbase + (((long)s) << 8) + l16b);
            acc[0] = fmaf(__uint_as_float(v.x << 16),         al, acc[0]);
            acc[1] = fmaf(__uint_as_float(v.x & 0xffff0000u), al, acc[1]);
            acc[2] = fmaf(__uint_as_float(v.y << 16),         al, acc[2]);
            acc[3] = fmaf(__uint_as_float(v.y & 0xffff0000u), al, acc[3]);
            acc[4] = fmaf(__uint_as_float(v.z << 16),         al, acc[4]);
            acc[5] = fmaf(__uint_as_float(v.z & 0xffff0000u), al, acc[5]);
            acc[6] = fmaf(__uint_as_float(v.w << 16),         al, acc[6]);
            acc[7] = fmaf(__uint_as_float(v.w & 0xffff0000u), al, acc[7]);
        }
    }

#pragma unroll
    for (int j = 0; j < 8; j++) {
        acc[j] += __shfl_xor(acc[j], 16);
        acc[j] += __shfl_xor(acc[j], 32);
    }

    int g = lane >> 4;
    float o0 = acc[0], o1 = acc[1];
    if (g == 1) { o0 = acc[2]; o1 = acc[3]; }
    if (g == 2) { o0 = acc[4]; o1 = acc[5]; }
    if (g == 3) { o0 = acc[6]; o1 = acc[7]; }
    int c = (l16 << 3) + (g << 1);
    float2 cA = *(const float2*)&coefA[c];
    float2 cB = *(const float2*)&coefB[c];
    float r0 = fmaxf(fmaf(o0, cA.x, cB.x), 0.f);
    float r1 = fmaxf(fmaf(o1, cA.y, cB.y), 0.f);
    unsigned oidx = (unsigned)(n * 64 + (l16 << 2) + g);
    if (OUTBF16) {
        unsigned int pk = (unsigned int)f2bf(r0) | ((unsigned int)f2bf(r1) << 16);
        ((unsigned int*)outv)[oidx] = pk;
    } else {
        ((float2*)outv)[oidx] = make_float2(r0, r1);
    }
}

// ---------------------------------------------------------------------------
// Dispatch wrappers (r6 proven schedule)
// ---------------------------------------------------------------------------
__global__ __launch_bounds__(256) void fused_scatter_gemm1a(
        const int* ei, int* cursor, int* binned,
        const float* x, const unsigned short* Wt1,
        const float* att_src, const float* att_dst,
        unsigned short* Hout, float* aS, float* aD) {
    __shared__ Smem sm;
    __shared__ int histL[NB];
    if (blockIdx.x < BIN_BLOCKS) {
        bin_scatter_body(histL, blockIdx.x, ei, cursor, binned);
    } else {
        gemm_att_body<false>(sm, blockIdx.x - BIN_BLOCKS, x, Wt1, att_src, att_dst,
                             Hout, aS, aD, 256);
    }
}

__global__ __launch_bounds__(256) void fused_finalize_gemm1b(
        const int* binned, const int* cursor,
        int* starts, int* degs, int* csr,
        const float* x, const unsigned short* Wt1,
        const float* att_src, const float* att_dst,
        unsigned short* Hout, float* aS, float* aD) {
    __shared__ Smem sm;
    __shared__ int histN[128];
    __shared__ int excl[128];
    if (blockIdx.x < NB) {
        bin_finalize_body(histN, excl, blockIdx.x, binned, cursor, starts, degs, csr);
    } else {
        gemm_att_body<false>(sm, blockIdx.x, x, Wt1, att_src, att_dst,
                             Hout, aS, aD, 256);
    }
}

template<bool XBF16>
__global__ __launch_bounds__(256) void gemm_att_kernel(const void* Xv,
                                                       const unsigned short* Wt,
                                                       const float* att_src,
                                                       const float* att_dst,
                                                       unsigned short* Hout,
                                                       float* aS, float* aD, int K) {
    __shared__ Smem sm;
    gemm_att_body<XBF16>(sm, blockIdx.x, Xv, Wt, att_src, att_dst, Hout, aS, aD, K);
}

template<bool OUTBF16>
__global__ __launch_bounds__(256) void gather_kernel(const unsigned short* hfeat,
                                                     const float* a_s, const float* a_d,
                                                     const int* starts, const int* degs,
                                                     const int* csr,
                                                     const float* coefA, const float* coefB,
                                                     void* outv) {
    gather_body<OUTBF16>((int)blockIdx.x, hfeat, a_s, a_d, starts, degs, csr,
                         coefA, coefB, outv);
}

// ---------------------------------------------------------------------------
extern "C" void kernel_launch(void* const* d_in, const int* in_sizes, int n_in,
                              void* d_out, int out_size, void* d_ws, size_t ws_size,
                              hipStream_t stream) {
    const float* x    = (const float*)d_in[0];
    const int*   ei   = (const int*)d_in[1];
    const float* W1   = (const float*)d_in[2];
    const float* as1  = (const float*)d_in[3];
    const float* ad1  = (const float*)d_in[4];
    const float* b1   = (const float*)d_in[5];
    const float* g1   = (const float*)d_in[6];
    const float* be1  = (const float*)d_in[7];
    const float* mn1  = (const float*)d_in[8];
    const float* vr1  = (const float*)d_in[9];
    const float* W2   = (const float*)d_in[10];
    const float* as2  = (const float*)d_in[11];
    const float* ad2  = (const float*)d_in[12];
    const float* b2   = (const float*)d_in[13];
    const float* g2   = (const float*)d_in[14];
    const float* be2  = (const float*)d_in[15];
    const float* mn2  = (const float*)d_in[16];
    const float* vr2  = (const float*)d_in[17];
    float* out = (float*)d_out;

    unsigned short* hbA = (unsigned short*)d_ws;                  // N*128 bf16
    unsigned short* x2b = hbA + (size_t)N_NODES * HID;            // N*128 bf16
    unsigned short* Wt1 = x2b + (size_t)N_NODES * HID;            // 128*256
    unsigned short* Wt2 = Wt1 + 128 * 256;                        // 128*128
    float* aS1   = (float*)(Wt2 + 128 * 128);                     // N*4
    float* aD1   = aS1 + N_NODES * NH;                            // N*4
    float* aS2   = aD1 + N_NODES * NH;                            // N*4
    float* aD2   = aS2 + N_NODES * NH;                            // N*4
    float* coef  = aD2 + N_NODES * NH;                            // 512
    int* cursor  = (int*)(coef + 512);                            // 512 (padded)
    int* starts  = cursor + 512;                                  // N
    int* degs    = starts + N_NODES;                              // N
    int* csr     = degs + N_NODES;                                // NB*BCAP
    int* binned  = csr + NB * BCAP;                               // NB*BCAP
    unsigned short* hbB = (unsigned short*)binned;                // overlay (disjoint live range)

    size_t need = (size_t)((char*)binned - (char*)d_ws) + (size_t)N_NODES * HID * 2;
    bool big = ws_size >= need;
    if (!big) { hbB = hbA; aS2 = aS1; aD2 = aD1; }

    int gemmGrid = GEMM_TILES;
    int nodeGrid = N_NODES / 4;

    wtrans_coef_kernel<<<128, 256, 0, stream>>>(W1, W2, Wt1, Wt2,
                                                b1, g1, be1, mn1, vr1,
                                                b2, g2, be2, mn2, vr2, coef, cursor);
    // D1: CSR bucket scatter (208) + GEMM1 tiles [0,391)
    fused_scatter_gemm1a<<<BIN_BLOCKS + NB, 256, 0, stream>>>(
        ei, cursor, binned, x, Wt1, as1, ad1, hbA, aS1, aD1);
    // D2: bucket finalize (391) + GEMM1 tiles [391,782)
    fused_finalize_gemm1b<<<gemmGrid, 256, 0, stream>>>(
        binned, cursor, starts, degs, csr, x, Wt1, as1, ad1, hbA, aS1, aD1);
    // D3: gather layer 1
    gather_kernel<true><<<nodeGrid, 256, 0, stream>>>(hbA, aS1, aD1, starts, degs, csr,
                                                      coef, coef + 128, (void*)x2b);
    // D4: GEMM2
    gemm_att_kernel<true><<<gemmGrid, 256, 0, stream>>>(x2b, Wt2, as2, ad2, hbB, aS2, aD2, 128);
    // D5: gather layer 2
    gather_kernel<false><<<nodeGrid, 256, 0, stream>>>(hbB, aS2, aD2, starts, degs, csr,
                                                       coef + 256, coef + 384, (void*)out);
}